// Round 3
// baseline (209.370 us; speedup 1.0000x reference)
//
#include <hip/hip_runtime.h>
#include <hip/hip_bf16.h>

typedef __bf16 bf16x8 __attribute__((ext_vector_type(8)));
typedef __bf16 bf16x4 __attribute__((ext_vector_type(4)));
typedef float  f32x4  __attribute__((ext_vector_type(4)));

#define MFMA16(A,B,C) __builtin_amdgcn_mfma_f32_16x16x32_bf16((A),(B),(C),0,0,0)

// LDS layout (bytes). Q/K: [head][112 tok][32 d] bf16, row stride 80B (pad -> conflict-free b128).
// Vt: [head][32 d][128 tok] bf16, stride 256B, XOR-swizzled. P: per-wave [16][128] swz. O: [112][128] swz.
constexpr int LQ = 0;
constexpr int LK = LQ + 4*112*80;        // 35840
constexpr int LV = LK + 4*112*80;        // 71680
constexpr int LP = LV + 4*32*256;        // 104448
constexpr int LO = LP + 4*16*256;        // 120832
constexpr int LDS_BYTES = LO + 112*256;  // 149504 (< 160 KiB)

__device__ __forceinline__ bf16x8 cvt8(float4 a, float4 b) {
    bf16x8 r;
    r[0]=(__bf16)a.x; r[1]=(__bf16)a.y; r[2]=(__bf16)a.z; r[3]=(__bf16)a.w;
    r[4]=(__bf16)b.x; r[5]=(__bf16)b.y; r[6]=(__bf16)b.z; r[7]=(__bf16)b.w;
    return r;
}

// addT[cls][head][j(key)][i(query)] = rel-pos bias + shift mask + (-1e30 if j>=98)
__global__ void swin_addt_kernel(const float* __restrict__ rpb, float* __restrict__ addT) {
    int idx = blockIdx.x * 256 + threadIdx.x;
    if (idx >= 8*4*112*112) return;
    int i   = idx % 112;
    int j   = (idx / 112) % 112;
    int h   = (idx / (112*112)) & 3;
    int cls = idx / (112*112*4);
    float v;
    if (j >= 98) v = -1e30f;          // key padding -> softmax zero
    else if (i >= 98) v = 0.0f;       // query padding rows: value irrelevant, keep finite
    else {
        int ti = i / 49, ri = i % 49, hi = ri / 7, wi = ri % 7;
        int tj = j / 49, rj = j % 49, hj = rj / 7, wj = rj % 7;
        int rel = (ti - tj + 1)*169 + (hi - hj + 6)*13 + (wi - wj + 6);
        v = rpb[rel*4 + h];
        int rt_i = (cls & 4) ? (1 + ti) : 0;
        int rh_i = (cls & 2) ? ((hi < 4) ? 1 : 2) : 0;
        int rw_i = (cls & 1) ? ((wi < 4) ? 1 : 2) : 0;
        int rt_j = (cls & 4) ? (1 + tj) : 0;
        int rh_j = (cls & 2) ? ((hj < 4) ? 1 : 2) : 0;
        int rw_j = (cls & 1) ? ((wj < 4) ? 1 : 2) : 0;
        if (rt_i*9 + rh_i*3 + rw_i != rt_j*9 + rh_j*3 + rw_j) v -= 100.0f;
    }
    addT[idx] = v;
}

__global__ __launch_bounds__(256, 1)
void swin_fused_kernel(const float* __restrict__ x, const float* __restrict__ qkv_w,
                       const float* __restrict__ proj_w, const float* __restrict__ proj_b,
                       const float* __restrict__ addT, float* __restrict__ out) {
    __shared__ __align__(16) unsigned char smem[LDS_BYTES];
    const int tid  = threadIdx.x;
    const int lane = tid & 63;
    const int wv   = tid >> 6;       // wave id == head
    const int l15  = lane & 15;
    const int l4   = lane >> 4;      // 0..3

    const int win  = blockIdx.x;     // (b, bt, bh, bw)
    const int b    = win >> 9;
    const int wr   = win & 511;
    const int bt   = wr >> 6, bh = (wr >> 3) & 7, bw = wr & 7;
    const int cls  = ((bt==7)?4:0) | ((bh==7)?2:0) | ((bw==7)?1:0);

    const f32x4 fz = {0.f, 0.f, 0.f, 0.f};

    // zero Vt pad columns n in [112,128) (read by PV k-step 3)
    for (int i = tid; i < 4*32*16; i += 256) {
        int n  = 112 + (i & 15);
        int d  = (i >> 4) & 31;
        int hh = i >> 9;
        *(__bf16*)(smem + LV + ((hh*32 + d) << 8) + ((2*n) ^ ((d & 7) << 4))) = (__bf16)0.0f;
    }

    // ======== Phase 1: QKV projection; wave wv produces head wv's q,k,v ========
    // col-sets cs: part = cs>>1 (0=q,1=k,2=v), dbase = (cs&1)*16. jcol = part*128 + wv*32 + dbase + l15.
    bf16x8 wfr[6][4];
    for (int cs = 0; cs < 6; ++cs) {
        int part = cs >> 1;
        int row  = part*128 + wv*32 + ((cs & 1) << 4) + l15;
        const float* wp = qkv_w + row*128 + l4*8;
        for (int ks = 0; ks < 4; ++ks)
            wfr[cs][ks] = cvt8(*(const float4*)(wp + ks*32), *(const float4*)(wp + ks*32 + 4));
    }
    const float kscale = 0.17677669529663687f;   // 32^-0.5
    for (int mt = 0; mt < 7; ++mt) {
        // A-fragment rows: gather rolled x directly (rolled[g] = x[(g+shift) mod dim])
        int n  = mt*16 + l15;
        int it = n / 49; int rr = n - it*49; int ih = rr / 7; int iw = rr - ih*7;
        int ts = (bt*2 + it + 1) & 15;
        int hs = bh*7 + ih + 3; if (hs >= 56) hs -= 56;
        int vs = bw*7 + iw + 3; if (vs >= 56) vs -= 56;
        const float* xp = x + (((b*16 + ts)*56 + hs)*56 + vs)*128 + l4*8;
        bf16x8 afr[4];
        for (int ks = 0; ks < 4; ++ks)
            afr[ks] = cvt8(*(const float4*)(xp + ks*32), *(const float4*)(xp + ks*32 + 4));
        f32x4 acc[6];
        for (int cs = 0; cs < 6; ++cs) acc[cs] = fz;
        for (int ks = 0; ks < 4; ++ks)
            for (int cs = 0; cs < 6; ++cs)
                acc[cs] = MFMA16(afr[ks], wfr[cs][ks], acc[cs]);
        for (int cs = 0; cs < 6; ++cs) {
            int part = cs >> 1;
            int d    = ((cs & 1) << 4) + l15;   // C-frag: col = l15, row = l4*4+r
            for (int r = 0; r < 4; ++r) {
                int nn = mt*16 + l4*4 + r;
                float v = acc[cs][r];
                if (part == 0)
                    *(__bf16*)(smem + LQ + (wv*112 + nn)*80 + d*2) = (__bf16)(v * kscale);
                else if (part == 1)
                    *(__bf16*)(smem + LK + (wv*112 + nn)*80 + d*2) = (__bf16)v;
                else
                    *(__bf16*)(smem + LV + ((wv*32 + d) << 8) + ((2*nn) ^ ((d & 7) << 4))) = (__bf16)v;
            }
        }
    }
    __syncthreads();

    // ======== Phase 2: attention, wave wv == head ========
    bf16x8 kfr[7];
    for (int nt = 0; nt < 7; ++nt)   // B-frag of K^T: col=token(l15), k=d (8 contig)
        kfr[nt] = *(const bf16x8*)(smem + LK + (wv*112 + nt*16 + l15)*80 + l4*16);
    bf16x8 vfr[4][2];
    for (int ks = 0; ks < 4; ++ks)   // B-frag of V: col=d(l15), k=token (8 contig via Vt)
        for (int dt = 0; dt < 2; ++dt) {
            int d = dt*16 + l15;
            vfr[ks][dt] = *(const bf16x8*)(smem + LV + ((wv*32 + d) << 8) + ((2*(ks*32 + l4*8)) ^ ((d & 7) << 4)));
        }
    {   // zero own P pad cols 112..127 (never rewritten)
        int row = l15, col = 112 + l4*4;
        bf16x4 z4; z4[0]=z4[1]=z4[2]=z4[3]=(__bf16)0.0f;
        *(bf16x4*)(smem + LP + wv*4096 + row*256 + ((2*col) ^ ((row & 7) << 4))) = z4;
    }
    const float* at = addT + (cls*4 + wv)*112*112;
    for (int mt = 0; mt < 7; ++mt) {
        bf16x8 qfr = *(const bf16x8*)(smem + LQ + (wv*112 + mt*16 + l15)*80 + l4*16);
        f32x4 s[7];
        for (int nt = 0; nt < 7; ++nt) s[nt] = MFMA16(qfr, kfr[nt], fz);
        for (int nt = 0; nt < 7; ++nt)   // bias + mask + key-pad, vectorized over the 4 query rows
            s[nt] += *(const f32x4*)(at + (nt*16 + l15)*112 + mt*16 + l4*4);
        float mx[4], sum[4];
        for (int r = 0; r < 4; ++r) {
            float m = s[0][r];
            for (int nt = 1; nt < 7; ++nt) m = fmaxf(m, s[nt][r]);
            m = fmaxf(m, __shfl_xor(m, 1));
            m = fmaxf(m, __shfl_xor(m, 2));
            m = fmaxf(m, __shfl_xor(m, 4));
            m = fmaxf(m, __shfl_xor(m, 8));
            mx[r] = m; sum[r] = 0.f;
        }
        for (int nt = 0; nt < 7; ++nt)
            for (int r = 0; r < 4; ++r) {
                float p = __expf(s[nt][r] - mx[r]);
                s[nt][r] = p;
                sum[r]  += p;
            }
        for (int r = 0; r < 4; ++r) {
            sum[r] += __shfl_xor(sum[r], 1);
            sum[r] += __shfl_xor(sum[r], 2);
            sum[r] += __shfl_xor(sum[r], 4);
            sum[r] += __shfl_xor(sum[r], 8);
        }
        // P -> LDS (C-layout scatter), then read back as A-fragments
        for (int nt = 0; nt < 7; ++nt)
            for (int r = 0; r < 4; ++r) {
                int prow = l4*4 + r, pcol = nt*16 + l15;
                *(__bf16*)(smem + LP + wv*4096 + prow*256 + ((2*pcol) ^ ((prow & 7) << 4))) = (__bf16)s[nt][r];
            }
        f32x4 o0 = fz, o1 = fz;
        for (int ks = 0; ks < 4; ++ks) {
            bf16x8 pfr = *(const bf16x8*)(smem + LP + wv*4096 + l15*256 + ((ks*64 + l4*16) ^ ((l15 & 7) << 4)));
            o0 = MFMA16(pfr, vfr[ks][0], o0);
            o1 = MFMA16(pfr, vfr[ks][1], o1);
        }
        for (int r = 0; r < 4; ++r) {
            int nn = mt*16 + l4*4 + r;
            float inv = 1.0f / sum[r];
            int c0 = wv*32 + l15;
            *(__bf16*)(smem + LO + nn*256 + ((2*c0) ^ ((nn & 7) << 4)))      = (__bf16)(o0[r] * inv);
            *(__bf16*)(smem + LO + nn*256 + ((2*(c0+16)) ^ ((nn & 7) << 4))) = (__bf16)(o1[r] * inv);
        }
    }
    __syncthreads();

    // ======== Phase 3: proj GEMM + window-reverse + un-roll scatter ========
    bf16x8 pw[2][4];
    float  pb[2];
    for (int nt2 = 0; nt2 < 2; ++nt2) {
        int c = wv*32 + nt2*16 + l15;
        const float* wp = proj_w + c*128 + l4*8;
        for (int ks = 0; ks < 4; ++ks)
            pw[nt2][ks] = cvt8(*(const float4*)(wp + ks*32), *(const float4*)(wp + ks*32 + 4));
        pb[nt2] = proj_b[c];
    }
    for (int mt = 0; mt < 7; ++mt) {
        bf16x8 afr[4];
        int arow = mt*16 + l15;
        for (int ks = 0; ks < 4; ++ks)
            afr[ks] = *(const bf16x8*)(smem + LO + arow*256 + ((ks*64 + l4*16) ^ ((arow & 7) << 4)));
        f32x4 a0 = fz, a1 = fz;
        for (int ks = 0; ks < 4; ++ks) {
            a0 = MFMA16(afr[ks], pw[0][ks], a0);
            a1 = MFMA16(afr[ks], pw[1][ks], a1);
        }
        for (int r = 0; r < 4; ++r) {
            int nn = mt*16 + l4*4 + r;
            if (nn >= 98) continue;
            int it = nn / 49; int rr = nn - it*49; int ih = rr / 7; int iw = rr - ih*7;
            int td = (bt*2 + it + 1) & 15;                 // final = roll(+shift) of rolled coords
            int hd = bh*7 + ih + 3; if (hd >= 56) hd -= 56;
            int wd = bw*7 + iw + 3; if (wd >= 56) wd -= 56;
            float* op = out + (((b*16 + td)*56 + hd)*56 + wd)*128;
            op[wv*32 + l15]      = a0[r] + pb[0];
            op[wv*32 + 16 + l15] = a1[r] + pb[1];
        }
    }
}

extern "C" void kernel_launch(void* const* d_in, const int* in_sizes, int n_in,
                              void* d_out, int out_size, void* d_ws, size_t ws_size,
                              hipStream_t stream) {
    const float* x      = (const float*)d_in[0];
    const float* qkv_w  = (const float*)d_in[1];
    const float* proj_w = (const float*)d_in[2];
    const float* proj_b = (const float*)d_in[3];
    const float* rpb    = (const float*)d_in[4];
    float* out  = (float*)d_out;
    float* addT = (float*)d_ws;   // 8*4*112*112*4 = 1,605,632 bytes

    swin_addt_kernel<<<(8*4*112*112 + 255)/256, 256, 0, stream>>>(rpb, addT);
    swin_fused_kernel<<<1024, 256, 0, stream>>>(x, qkv_w, proj_w, proj_b, addT, out);
}

// Round 4
// 181.387 us; speedup vs baseline: 1.1543x; 1.1543x over previous
//
#include <hip/hip_runtime.h>
#include <hip/hip_bf16.h>

typedef __bf16 bf16x8 __attribute__((ext_vector_type(8)));
typedef __bf16 bf16x4 __attribute__((ext_vector_type(4)));
typedef float  f32x4  __attribute__((ext_vector_type(4)));

#define MFMA16(A,B,C) __builtin_amdgcn_mfma_f32_16x16x32_bf16((A),(B),(C),0,0,0)

// LDS layout (bytes), time-multiplexed:
//   Phase 1 (+preload): K [4 head][112 tok][80B row]  at 0      (35840)
//                       Vt [4 head][32 d][256B swz]   at 35840  (32768)  -> end 68608
//   After preload barrier (K/V dead, kfr/vfr in regs):
//                       P  [4 wave][16][256B swz]     at 0      (16384)
//                       O  [112][256B swz]            at 16384  (28672)
//                       QS [4 wave][7 tile][16][64B]  at 45056  (28672)  -> end 73728
// 73728 <= 80 KiB -> 2 blocks/CU (was 149504 -> 1 block/CU).
constexpr int LK  = 0;
constexpr int LV  = 35840;
constexpr int LP  = 0;
constexpr int LO  = 16384;
constexpr int LQS = 45056;
constexpr int LDS_BYTES = 73728;

__device__ __forceinline__ bf16x8 cvt8(float4 a, float4 b) {
    bf16x8 r;
    r[0]=(__bf16)a.x; r[1]=(__bf16)a.y; r[2]=(__bf16)a.z; r[3]=(__bf16)a.w;
    r[4]=(__bf16)b.x; r[5]=(__bf16)b.y; r[6]=(__bf16)b.z; r[7]=(__bf16)b.w;
    return r;
}

// addT[cls][head][j(key)][i(query)] = rel-pos bias + shift mask + (-1e30 if j>=98)
__global__ void swin_addt_kernel(const float* __restrict__ rpb, float* __restrict__ addT) {
    int idx = blockIdx.x * 256 + threadIdx.x;
    if (idx >= 8*4*112*112) return;
    int i   = idx % 112;
    int j   = (idx / 112) % 112;
    int h   = (idx / (112*112)) & 3;
    int cls = idx / (112*112*4);
    float v;
    if (j >= 98) v = -1e30f;          // key padding -> softmax zero
    else if (i >= 98) v = 0.0f;       // query padding rows: value irrelevant, keep finite
    else {
        int ti = i / 49, ri = i % 49, hi = ri / 7, wi = ri % 7;
        int tj = j / 49, rj = j % 49, hj = rj / 7, wj = rj % 7;
        int rel = (ti - tj + 1)*169 + (hi - hj + 6)*13 + (wi - wj + 6);
        v = rpb[rel*4 + h];
        int rt_i = (cls & 4) ? (1 + ti) : 0;
        int rh_i = (cls & 2) ? ((hi < 4) ? 1 : 2) : 0;
        int rw_i = (cls & 1) ? ((wi < 4) ? 1 : 2) : 0;
        int rt_j = (cls & 4) ? (1 + tj) : 0;
        int rh_j = (cls & 2) ? ((hj < 4) ? 1 : 2) : 0;
        int rw_j = (cls & 1) ? ((wj < 4) ? 1 : 2) : 0;
        if (rt_i*9 + rh_i*3 + rw_i != rt_j*9 + rh_j*3 + rw_j) v -= 100.0f;
    }
    addT[idx] = v;
}

__global__ __launch_bounds__(256, 2)
void swin_fused_kernel(const float* __restrict__ x, const float* __restrict__ qkv_w,
                       const float* __restrict__ proj_w, const float* __restrict__ proj_b,
                       const float* __restrict__ addT, float* __restrict__ out) {
    __shared__ __align__(16) unsigned char smem[LDS_BYTES];
    const int tid  = threadIdx.x;
    const int lane = tid & 63;
    const int wv   = tid >> 6;       // wave id == head
    const int l15  = lane & 15;
    const int l4   = lane >> 4;      // 0..3

    const int win  = blockIdx.x;     // (b, bt, bh, bw)
    const int b    = win >> 9;
    const int wr   = win & 511;
    const int bt   = wr >> 6, bh = (wr >> 3) & 7, bw = wr & 7;
    const int cls  = ((bt==7)?4:0) | ((bh==7)?2:0) | ((bw==7)?1:0);

    const f32x4 fz = {0.f, 0.f, 0.f, 0.f};

    // zero Vt pad tokens n in [112,128) (read by PV k-step 3)
    for (int i = tid; i < 4*32*16; i += 256) {
        int n  = 112 + (i & 15);
        int d  = (i >> 4) & 31;
        int hh = i >> 9;
        *(__bf16*)(smem + LV + ((hh*32 + d) << 8) + ((2*n) ^ ((d & 7) << 4))) = (__bf16)0.0f;
    }

    // ======== Phase 1: QKV projection; wave wv produces head wv's q,k,v ========
    // col-sets cs: part = cs>>1 (0=q,1=k,2=v), dbase = (cs&1)*16. jcol = part*128 + wv*32 + dbase + l15.
    bf16x8 wfr[6][4];
    for (int cs = 0; cs < 6; ++cs) {
        int part = cs >> 1;
        int row  = part*128 + wv*32 + ((cs & 1) << 4) + l15;
        const float* wp = qkv_w + row*128 + l4*8;
        for (int ks = 0; ks < 4; ++ks)
            wfr[cs][ks] = cvt8(*(const float4*)(wp + ks*32), *(const float4*)(wp + ks*32 + 4));
    }
    const float kscale = 0.17677669529663687f;   // 32^-0.5
    bf16x8 q_save[7];                             // q carried in regs (statically indexed)
    #pragma unroll
    for (int mt = 0; mt < 7; ++mt) {
        // A-fragment rows: gather rolled x directly (rolled[g] = x[(g+shift) mod dim])
        int n  = mt*16 + l15;
        int it = n / 49; int rr = n - it*49; int ih = rr / 7; int iw = rr - ih*7;
        int ts = (bt*2 + it + 1) & 15;
        int hs = bh*7 + ih + 3; if (hs >= 56) hs -= 56;
        int vs = bw*7 + iw + 3; if (vs >= 56) vs -= 56;
        const float* xp = x + (((b*16 + ts)*56 + hs)*56 + vs)*128 + l4*8;
        bf16x8 afr[4];
        for (int ks = 0; ks < 4; ++ks)
            afr[ks] = cvt8(*(const float4*)(xp + ks*32), *(const float4*)(xp + ks*32 + 4));
        f32x4 acc[6];
        for (int cs = 0; cs < 6; ++cs) acc[cs] = fz;
        for (int ks = 0; ks < 4; ++ks)
            for (int cs = 0; cs < 6; ++cs)
                acc[cs] = MFMA16(afr[ks], wfr[cs][ks], acc[cs]);
        // q -> registers (pre-scaled, bf16-packed); element e = (cs&1)*4 + r
        bf16x8 qs;
        #pragma unroll
        for (int r = 0; r < 4; ++r) {
            qs[r]     = (__bf16)(acc[0][r] * kscale);
            qs[r + 4] = (__bf16)(acc[1][r] * kscale);
        }
        q_save[mt] = qs;
        // k, v -> LDS (C-frag: col = l15, row = l4*4+r)
        #pragma unroll
        for (int cs = 2; cs < 6; ++cs) {
            int part = cs >> 1;
            int d    = ((cs & 1) << 4) + l15;
            for (int r = 0; r < 4; ++r) {
                int nn = mt*16 + l4*4 + r;
                float v = acc[cs][r];
                if (part == 1)
                    *(__bf16*)(smem + LK + (wv*112 + nn)*80 + d*2) = (__bf16)v;
                else
                    *(__bf16*)(smem + LV + ((wv*32 + d) << 8) + ((2*nn) ^ ((d & 7) << 4))) = (__bf16)v;
            }
        }
    }
    __syncthreads();

    // ======== Phase 2 entry: preload K,V fragments (then K/V LDS is dead) ========
    bf16x8 kfr[7];
    for (int nt = 0; nt < 7; ++nt)   // B-frag of K^T: col=token(l15), k=d (8 contig)
        kfr[nt] = *(const bf16x8*)(smem + LK + (wv*112 + nt*16 + l15)*80 + l4*16);
    bf16x8 vfr[4][2];
    for (int ks = 0; ks < 4; ++ks)   // B-frag of V: col=d(l15), k=token (8 contig via Vt)
        for (int dt = 0; dt < 2; ++dt) {
            int d = dt*16 + l15;
            vfr[ks][dt] = *(const bf16x8*)(smem + LV + ((wv*32 + d) << 8) + ((2*(ks*32 + l4*8)) ^ ((d & 7) << 4)));
        }
    __syncthreads();   // after this, P/O/QS may alias the K/V region

    // stage all q tiles to per-wave scratch [16 tok][64B row] (conflict-free b128 reads)
    #pragma unroll
    for (int t = 0; t < 7; ++t) {
        bf16x8 qs = q_save[t];
        #pragma unroll
        for (int e = 0; e < 8; ++e) {
            int token = l4*4 + (e & 3);
            int d     = ((e >> 2) << 4) + l15;
            *(__bf16*)(smem + LQS + wv*7168 + t*1024 + token*64 + d*2) = qs[e];
        }
    }
    {   // zero own P pad cols 112..127 (never rewritten)
        int row = l15, col = 112 + l4*4;
        bf16x4 z4; z4[0]=z4[1]=z4[2]=z4[3]=(__bf16)0.0f;
        *(bf16x4*)(smem + LP + wv*4096 + row*256 + ((2*col) ^ ((row & 7) << 4))) = z4;
    }
    const float* at = addT + (cls*4 + wv)*112*112;
    for (int mt = 0; mt < 7; ++mt) {
        bf16x8 qfr = *(const bf16x8*)(smem + LQS + wv*7168 + mt*1024 + l15*64 + l4*16);
        f32x4 s[7];
        for (int nt = 0; nt < 7; ++nt) s[nt] = MFMA16(qfr, kfr[nt], fz);
        for (int nt = 0; nt < 7; ++nt)   // bias + mask + key-pad, vectorized over the 4 query rows
            s[nt] += *(const f32x4*)(at + (nt*16 + l15)*112 + mt*16 + l4*4);
        float mx[4], sum[4];
        for (int r = 0; r < 4; ++r) {
            float m = s[0][r];
            for (int nt = 1; nt < 7; ++nt) m = fmaxf(m, s[nt][r]);
            m = fmaxf(m, __shfl_xor(m, 1));
            m = fmaxf(m, __shfl_xor(m, 2));
            m = fmaxf(m, __shfl_xor(m, 4));
            m = fmaxf(m, __shfl_xor(m, 8));
            mx[r] = m; sum[r] = 0.f;
        }
        for (int nt = 0; nt < 7; ++nt)
            for (int r = 0; r < 4; ++r) {
                float p = __expf(s[nt][r] - mx[r]);
                s[nt][r] = p;
                sum[r]  += p;
            }
        for (int r = 0; r < 4; ++r) {
            sum[r] += __shfl_xor(sum[r], 1);
            sum[r] += __shfl_xor(sum[r], 2);
            sum[r] += __shfl_xor(sum[r], 4);
            sum[r] += __shfl_xor(sum[r], 8);
        }
        // P -> LDS (C-layout scatter), then read back as A-fragments
        for (int nt = 0; nt < 7; ++nt)
            for (int r = 0; r < 4; ++r) {
                int prow = l4*4 + r, pcol = nt*16 + l15;
                *(__bf16*)(smem + LP + wv*4096 + prow*256 + ((2*pcol) ^ ((prow & 7) << 4))) = (__bf16)s[nt][r];
            }
        f32x4 o0 = fz, o1 = fz;
        for (int ks = 0; ks < 4; ++ks) {
            bf16x8 pfr = *(const bf16x8*)(smem + LP + wv*4096 + l15*256 + ((ks*64 + l4*16) ^ ((l15 & 7) << 4)));
            o0 = MFMA16(pfr, vfr[ks][0], o0);
            o1 = MFMA16(pfr, vfr[ks][1], o1);
        }
        for (int r = 0; r < 4; ++r) {
            int nn = mt*16 + l4*4 + r;
            float inv = 1.0f / sum[r];
            int c0 = wv*32 + l15;
            *(__bf16*)(smem + LO + nn*256 + ((2*c0) ^ ((nn & 7) << 4)))      = (__bf16)(o0[r] * inv);
            *(__bf16*)(smem + LO + nn*256 + ((2*(c0+16)) ^ ((nn & 7) << 4))) = (__bf16)(o1[r] * inv);
        }
    }
    __syncthreads();

    // ======== Phase 3: proj GEMM + window-reverse + un-roll scatter ========
    bf16x8 pw[2][4];
    float  pb[2];
    for (int nt2 = 0; nt2 < 2; ++nt2) {
        int c = wv*32 + nt2*16 + l15;
        const float* wp = proj_w + c*128 + l4*8;
        for (int ks = 0; ks < 4; ++ks)
            pw[nt2][ks] = cvt8(*(const float4*)(wp + ks*32), *(const float4*)(wp + ks*32 + 4));
        pb[nt2] = proj_b[c];
    }
    for (int mt = 0; mt < 7; ++mt) {
        bf16x8 afr[4];
        int arow = mt*16 + l15;
        for (int ks = 0; ks < 4; ++ks)
            afr[ks] = *(const bf16x8*)(smem + LO + arow*256 + ((ks*64 + l4*16) ^ ((arow & 7) << 4)));
        f32x4 a0 = fz, a1 = fz;
        for (int ks = 0; ks < 4; ++ks) {
            a0 = MFMA16(afr[ks], pw[0][ks], a0);
            a1 = MFMA16(afr[ks], pw[1][ks], a1);
        }
        for (int r = 0; r < 4; ++r) {
            int nn = mt*16 + l4*4 + r;
            if (nn >= 98) continue;
            int it = nn / 49; int rr = nn - it*49; int ih = rr / 7; int iw = rr - ih*7;
            int td = (bt*2 + it + 1) & 15;                 // final = roll(+shift) of rolled coords
            int hd = bh*7 + ih + 3; if (hd >= 56) hd -= 56;
            int wd = bw*7 + iw + 3; if (wd >= 56) wd -= 56;
            float* op = out + (((b*16 + td)*56 + hd)*56 + wd)*128;
            op[wv*32 + l15]      = a0[r] + pb[0];
            op[wv*32 + 16 + l15] = a1[r] + pb[1];
        }
    }
}

extern "C" void kernel_launch(void* const* d_in, const int* in_sizes, int n_in,
                              void* d_out, int out_size, void* d_ws, size_t ws_size,
                              hipStream_t stream) {
    const float* x      = (const float*)d_in[0];
    const float* qkv_w  = (const float*)d_in[1];
    const float* proj_w = (const float*)d_in[2];
    const float* proj_b = (const float*)d_in[3];
    const float* rpb    = (const float*)d_in[4];
    float* out  = (float*)d_out;
    float* addT = (float*)d_ws;   // 8*4*112*112*4 = 1,605,632 bytes

    swin_addt_kernel<<<(8*4*112*112 + 255)/256, 256, 0, stream>>>(rpb, addT);
    swin_fused_kernel<<<1024, 256, 0, stream>>>(x, qkv_w, proj_w, proj_b, addT, out);
}